// Round 1
// baseline (3161.124 us; speedup 1.0000x reference)
//
#include <hip/hip_runtime.h>
#include <cmath>

#define B_ROWS 16384
#define IN_DIM 784
#define N_HID  2000
#define K_WIN  200

// ---------------------------------------------------------------------------
// Phase 0: boost[i] = exp((k/n - dutyCycle[i]) * boostStrength), fp64
// ---------------------------------------------------------------------------
__global__ __launch_bounds__(256) void boost_kernel(const float* __restrict__ duty,
                                                    double* __restrict__ boost) {
    int i = blockIdx.x * 256 + threadIdx.x;
    if (i < N_HID) boost[i] = exp(0.1 - (double)duty[i]);
}

// ---------------------------------------------------------------------------
// Phase 1: h = x @ W1^T + b1 in fp64.  x:[B,784] W1:[2000,784] both row-major
// (both K-contiguous).  64x64 tile, 16-wide K chunk, 4x4 microtile/thread.
// HT = storage type of h in workspace (double preferred, float fallback).
// ---------------------------------------------------------------------------
template <typename HT>
__global__ __launch_bounds__(256) void gemm_fp64_kernel(const float* __restrict__ x,
                                                        const float* __restrict__ w1,
                                                        const float* __restrict__ b1,
                                                        HT* __restrict__ h) {
    __shared__ double As[16][65];   // [k][m], +1 pad
    __shared__ double Bs[16][65];   // [k][n]
    const int tid = threadIdx.x;
    const int n0 = blockIdx.x * 64;
    const int m0 = blockIdx.y * 64;
    const int tx = tid & 15;        // n-direction microtile
    const int ty = tid >> 4;        // m-direction microtile
    const int lr = tid >> 2;        // 0..63: row within tile for staging
    const int lk = (tid & 3) << 2;  // 0,4,8,12: k offset for float4 load

    double acc[4][4] = {};

    for (int k0 = 0; k0 < IN_DIM; k0 += 16) {
        float4 xa = *(const float4*)(x + (size_t)(m0 + lr) * IN_DIM + (k0 + lk));
        float4 wb = make_float4(0.f, 0.f, 0.f, 0.f);
        const int n = n0 + lr;
        if (n < N_HID)
            wb = *(const float4*)(w1 + (size_t)n * IN_DIM + (k0 + lk));
        __syncthreads();   // previous iter's compute done before overwrite
        As[lk + 0][lr] = (double)xa.x;
        As[lk + 1][lr] = (double)xa.y;
        As[lk + 2][lr] = (double)xa.z;
        As[lk + 3][lr] = (double)xa.w;
        Bs[lk + 0][lr] = (double)wb.x;
        Bs[lk + 1][lr] = (double)wb.y;
        Bs[lk + 2][lr] = (double)wb.z;
        Bs[lk + 3][lr] = (double)wb.w;
        __syncthreads();
        #pragma unroll
        for (int kk = 0; kk < 16; ++kk) {
            double a[4], b[4];
            #pragma unroll
            for (int i = 0; i < 4; ++i) a[i] = As[kk][ty * 4 + i];
            #pragma unroll
            for (int j = 0; j < 4; ++j) b[j] = Bs[kk][tx * 4 + j];
            #pragma unroll
            for (int i = 0; i < 4; ++i)
                #pragma unroll
                for (int j = 0; j < 4; ++j)
                    acc[i][j] = fma(a[i], b[j], acc[i][j]);
        }
    }

    #pragma unroll
    for (int i = 0; i < 4; ++i) {
        const int m = m0 + ty * 4 + i;
        #pragma unroll
        for (int j = 0; j < 4; ++j) {
            const int n = n0 + tx * 4 + j;
            if (n < N_HID)
                h[(size_t)m * N_HID + n] = (HT)(acc[i][j] + (double)b1[n]);
        }
    }
}

// ---------------------------------------------------------------------------
// Phase 2: per row — boosted = h*boost, exact K-th-largest via 8-pass byte
// radix select on monotone-mapped fp64 keys, winners keep ORIGINAL h, then
// logits = sum_winners h_i * W2[:,i] + b2, log_softmax, write fp32.
// Tie semantics match jax.lax.top_k: among equal boosted values, lower index
// wins.
// ---------------------------------------------------------------------------
template <typename HT>
__global__ __launch_bounds__(256) void topk_logits_kernel(const HT* __restrict__ h,
                                                          const double* __restrict__ boost,
                                                          const float* __restrict__ w2,
                                                          const float* __restrict__ b2,
                                                          float* __restrict__ out) {
    __shared__ double sh[N_HID];                 // original h values
    __shared__ unsigned long long sk[N_HID];     // monotone keys of boosted
    __shared__ unsigned int hist[256];
    __shared__ double partial[4][10];
    __shared__ unsigned long long s_prefix;
    __shared__ int s_r;
    __shared__ unsigned int s_GE[2];

    const int row = blockIdx.x;
    const int tid = threadIdx.x;
    const HT* hrow = h + (size_t)row * N_HID;

    // Load row, build keys: monotone uint64 of (h * boost)
    for (int i = tid; i < N_HID; i += 256) {
        double v = (double)hrow[i];
        sh[i] = v;
        double bv = v * boost[i];
        unsigned long long u = (unsigned long long)__double_as_longlong(bv);
        u = (u >> 63) ? ~u : (u | 0x8000000000000000ULL);
        sk[i] = u;
    }
    if (tid == 0) { s_prefix = 0ULL; s_r = K_WIN; }
    __syncthreads();

    // 8-pass radix select, high byte -> low byte, descending rank K_WIN
    for (int pass = 7; pass >= 0; --pass) {
        hist[tid] = 0u;
        __syncthreads();
        const unsigned long long pref = s_prefix;
        const int r = s_r;
        const int shift = pass * 8;
        const unsigned long long himask =
            (pass == 7) ? 0ULL : (~0ULL << (shift + 8));
        for (int i = tid; i < N_HID; i += 256) {
            unsigned long long k = sk[i];
            if (((k ^ pref) & himask) == 0ULL)
                atomicAdd(&hist[(unsigned)(k >> shift) & 255u], 1u);
        }
        __syncthreads();
        // inclusive suffix sum over hist (Hillis-Steele)
        for (int d = 1; d < 256; d <<= 1) {
            unsigned v = (tid + d < 256) ? hist[tid + d] : 0u;
            __syncthreads();
            hist[tid] += v;
            __syncthreads();
        }
        const unsigned incl = hist[tid];                       // count byte >= tid
        const unsigned excl = (tid < 255) ? hist[tid + 1] : 0; // count byte >  tid
        if ((int)incl >= r && (int)excl < r) {                 // exactly one thread
            s_prefix = pref | ((unsigned long long)(unsigned)tid << shift);
            s_r = r - (int)excl;
        }
        __syncthreads();
    }

    const unsigned long long tkey = s_prefix;  // exact key of K-th largest
    if (tid < 2) s_GE[tid] = 0u;
    __syncthreads();
    {
        unsigned g = 0, e = 0;
        for (int i = tid; i < N_HID; i += 256) {
            unsigned long long k = sk[i];
            g += (k > tkey);
            e += (k == tkey);
        }
        if (g) atomicAdd(&s_GE[0], g);
        if (e) atomicAdd(&s_GE[1], e);
    }
    __syncthreads();
    const int G = (int)s_GE[0];
    const int take_eq = K_WIN - G;  // >=1 equals to take, by lowest index

    // Accumulate logits over winners
    double l[10];
    #pragma unroll
    for (int c = 0; c < 10; ++c) l[c] = 0.0;
    for (int i = tid; i < N_HID; i += 256) {
        const unsigned long long k = sk[i];
        bool win = (k > tkey);
        if (!win && k == tkey) {
            int rnk = 0;  // index-rank among equals (rare: usually 1 equal)
            for (int j = 0; j < i; ++j) rnk += (sk[j] == tkey);
            win = (rnk < take_eq);
        }
        if (win) {
            const double hv = sh[i];
            #pragma unroll
            for (int c = 0; c < 10; ++c)
                l[c] += hv * (double)w2[c * N_HID + i];
        }
    }
    // wave reduce then cross-wave
    #pragma unroll
    for (int off = 32; off > 0; off >>= 1) {
        #pragma unroll
        for (int c = 0; c < 10; ++c)
            l[c] += __shfl_down(l[c], off);
    }
    const int wave = tid >> 6;
    if ((tid & 63) == 0) {
        #pragma unroll
        for (int c = 0; c < 10; ++c) partial[wave][c] = l[c];
    }
    __syncthreads();
    if (tid == 0) {
        double lg[10];
        #pragma unroll
        for (int c = 0; c < 10; ++c)
            lg[c] = partial[0][c] + partial[1][c] + partial[2][c] + partial[3][c] +
                    (double)b2[c];
        double mx = lg[0];
        #pragma unroll
        for (int c = 1; c < 10; ++c) mx = fmax(mx, lg[c]);
        double s = 0.0;
        #pragma unroll
        for (int c = 0; c < 10; ++c) s += exp(lg[c] - mx);
        const double lse = mx + log(s);
        #pragma unroll
        for (int c = 0; c < 10; ++c)
            out[(size_t)row * 10 + c] = (float)(lg[c] - lse);
    }
}

// ---------------------------------------------------------------------------
extern "C" void kernel_launch(void* const* d_in, const int* in_sizes, int n_in,
                              void* d_out, int out_size, void* d_ws, size_t ws_size,
                              hipStream_t stream) {
    const float* x    = (const float*)d_in[0];
    const float* w1   = (const float*)d_in[1];
    const float* b1   = (const float*)d_in[2];
    const float* w2   = (const float*)d_in[3];
    const float* b2   = (const float*)d_in[4];
    const float* duty = (const float*)d_in[5];
    float* out = (float*)d_out;

    double* boost = (double*)d_ws;                       // 2000 doubles
    const size_t hoff = 2048 * sizeof(double);           // 16 KiB, keeps h aligned
    const size_t need_fp64 = hoff + (size_t)B_ROWS * N_HID * sizeof(double);

    boost_kernel<<<8, 256, 0, stream>>>(duty, boost);

    if (ws_size >= need_fp64) {
        double* h = (double*)((char*)d_ws + hoff);
        gemm_fp64_kernel<double><<<dim3(32, 256), 256, 0, stream>>>(x, w1, b1, h);
        topk_logits_kernel<double><<<B_ROWS, 256, 0, stream>>>(h, boost, w2, b2, out);
    } else {
        float* h = (float*)((char*)d_ws + hoff);
        gemm_fp64_kernel<float><<<dim3(32, 256), 256, 0, stream>>>(x, w1, b1, h);
        topk_logits_kernel<float><<<B_ROWS, 256, 0, stream>>>(h, boost, w2, b2, out);
    }
}

// Round 2
// 1138.912 us; speedup vs baseline: 2.7756x; 2.7756x over previous
//
#include <hip/hip_runtime.h>
#include <cmath>

#define B_ROWS 16384
#define IN_DIM 784
#define N_HID  2000
#define K_WIN  200

// ---------------------------------------------------------------------------
// Phase 0: boost[i] = expf(0.1f - duty[i])  (fp32, matches np float32 arith)
// ---------------------------------------------------------------------------
__global__ __launch_bounds__(256) void boost_kernel(const float* __restrict__ duty,
                                                    float* __restrict__ boost) {
    int i = blockIdx.x * 256 + threadIdx.x;
    if (i < N_HID) boost[i] = expf(0.1f - duty[i]);
}

// ---------------------------------------------------------------------------
// Phase 1: h = x @ W1^T + b1, fp32.  x:[B,784], W1:[2000,784], both row-major
// (K-contiguous).  128x128 tile, BK=16, 256 threads, 8x8 microtile/thread.
// Per K-chunk per thread: 1024 FMA vs 4 ds_read_b128  -> VALU-bound.
// ---------------------------------------------------------------------------
__global__ __launch_bounds__(256) void gemm_fp32_kernel(const float* __restrict__ x,
                                                        const float* __restrict__ w1,
                                                        const float* __restrict__ b1,
                                                        float* __restrict__ h) {
    __shared__ float As[16][132];   // [k][m], +4 pad
    __shared__ float Bs[16][132];   // [k][n]
    const int tid = threadIdx.x;
    const int n0 = blockIdx.x * 128;
    const int m0 = blockIdx.y * 128;
    const int tx = tid & 15;        // n microtile
    const int ty = tid >> 4;        // m microtile
    const int r  = tid >> 2;        // 0..63 staging row
    const int c  = (tid & 3) << 2;  // 0,4,8,12 staging k-offset

    // B row indices (clamp OOB to 1999; stores are guarded)
    const int nb0 = n0 + r;
    const int nb1 = (n0 + r + 64 < N_HID) ? (n0 + r + 64) : (N_HID - 1);

    float acc[8][8] = {};

    for (int k0 = 0; k0 < IN_DIM; k0 += 16) {
        float4 a0 = *(const float4*)(x  + (size_t)(m0 + r)      * IN_DIM + k0 + c);
        float4 a1 = *(const float4*)(x  + (size_t)(m0 + r + 64) * IN_DIM + k0 + c);
        float4 b0 = *(const float4*)(w1 + (size_t)nb0           * IN_DIM + k0 + c);
        float4 b1v= *(const float4*)(w1 + (size_t)nb1           * IN_DIM + k0 + c);
        __syncthreads();   // previous iteration's compute done
        As[c + 0][r] = a0.x;  As[c + 1][r] = a0.y;  As[c + 2][r] = a0.z;  As[c + 3][r] = a0.w;
        As[c + 0][r + 64] = a1.x;  As[c + 1][r + 64] = a1.y;  As[c + 2][r + 64] = a1.z;  As[c + 3][r + 64] = a1.w;
        Bs[c + 0][r] = b0.x;  Bs[c + 1][r] = b0.y;  Bs[c + 2][r] = b0.z;  Bs[c + 3][r] = b0.w;
        Bs[c + 0][r + 64] = b1v.x; Bs[c + 1][r + 64] = b1v.y; Bs[c + 2][r + 64] = b1v.z; Bs[c + 3][r + 64] = b1v.w;
        __syncthreads();
        #pragma unroll
        for (int kk = 0; kk < 16; ++kk) {
            float a[8], b[8];
            *(float4*)&a[0] = *(const float4*)&As[kk][ty * 8];
            *(float4*)&a[4] = *(const float4*)&As[kk][ty * 8 + 4];
            *(float4*)&b[0] = *(const float4*)&Bs[kk][tx * 8];
            *(float4*)&b[4] = *(const float4*)&Bs[kk][tx * 8 + 4];
            #pragma unroll
            for (int i = 0; i < 8; ++i)
                #pragma unroll
                for (int j = 0; j < 8; ++j)
                    acc[i][j] = fmaf(a[i], b[j], acc[i][j]);
        }
    }

    const int nbase = n0 + tx * 8;
    #pragma unroll
    for (int i = 0; i < 8; ++i) {
        const int m = m0 + ty * 8 + i;
        float* hrow = h + (size_t)m * N_HID + nbase;
        if (nbase + 7 < N_HID) {
            float4 v0, v1;
            v0.x = acc[i][0] + b1[nbase + 0];
            v0.y = acc[i][1] + b1[nbase + 1];
            v0.z = acc[i][2] + b1[nbase + 2];
            v0.w = acc[i][3] + b1[nbase + 3];
            v1.x = acc[i][4] + b1[nbase + 4];
            v1.y = acc[i][5] + b1[nbase + 5];
            v1.z = acc[i][6] + b1[nbase + 6];
            v1.w = acc[i][7] + b1[nbase + 7];
            *(float4*)hrow       = v0;
            *(float4*)(hrow + 4) = v1;
        } else {
            #pragma unroll
            for (int j = 0; j < 8; ++j)
                if (nbase + j < N_HID) hrow[j] = acc[i][j] + b1[nbase + j];
        }
    }
}

// ---------------------------------------------------------------------------
// Phase 2: per row — boosted = h*boost (fp32), exact K-th largest via 4-pass
// byte radix select on monotone u32 keys, winners keep ORIGINAL h, logits in
// fp32, log_softmax, write fp32.  Ties: lower index wins (jax top_k).
// ---------------------------------------------------------------------------
__global__ __launch_bounds__(256) void topk_logits_kernel(const float* __restrict__ h,
                                                          const float* __restrict__ boost,
                                                          const float* __restrict__ w2,
                                                          const float* __restrict__ b2,
                                                          float* __restrict__ out) {
    __shared__ float sh[N_HID];
    __shared__ unsigned sk[N_HID];
    __shared__ unsigned hist[260] __attribute__((aligned(16)));  // [256]..[259] pad, [256]=0
    __shared__ float partial[4][10];
    __shared__ unsigned s_prefix;
    __shared__ int s_r;
    __shared__ unsigned s_GE[2];

    const int row = blockIdx.x;
    const int tid = threadIdx.x;
    const float* hrow = h + (size_t)row * N_HID;

    for (int i = tid; i < N_HID; i += 256) {
        float v = hrow[i];
        sh[i] = v;
        unsigned u = __float_as_uint(v * boost[i]);
        sk[i] = (u >> 31) ? ~u : (u | 0x80000000u);
    }
    if (tid == 0) { s_prefix = 0u; s_r = K_WIN; hist[256] = 0u; }
    __syncthreads();

    // 4-pass radix select (high byte -> low), descending rank K_WIN
    for (int pass = 3; pass >= 0; --pass) {
        hist[tid] = 0u;
        __syncthreads();
        const unsigned pref = s_prefix;
        const int r = s_r;
        const int shift = pass * 8;
        const unsigned himask = (pass == 3) ? 0u : (~0u << (shift + 8));
        for (int i = tid; i < N_HID; i += 256) {
            unsigned k = sk[i];
            if (((k ^ pref) & himask) == 0u)
                atomicAdd(&hist[(k >> shift) & 255u], 1u);
        }
        __syncthreads();
        // wave 0: suffix sums over 256 bins (4 bins/lane + lane suffix scan)
        if (tid < 64) {
            uint4 u = *(const uint4*)&hist[tid * 4];
            unsigned ls3 = u.w;
            unsigned ls2 = u.z + ls3;
            unsigned ls1 = u.y + ls2;
            unsigned ls0 = u.x + ls1;
            unsigned s = ls0;
            #pragma unroll
            for (int off = 1; off < 64; off <<= 1) {
                unsigned t = __shfl_down(s, off);
                if (tid + off < 64) s += t;
            }
            const unsigned above = s - ls0;  // sum over lanes > tid
            hist[tid * 4 + 0] = ls0 + above;
            hist[tid * 4 + 1] = ls1 + above;
            hist[tid * 4 + 2] = ls2 + above;
            hist[tid * 4 + 3] = ls3 + above;
        }
        __syncthreads();
        const unsigned incl = hist[tid];      // count of keys with byte >= tid
        const unsigned excl = hist[tid + 1];  // count with byte > tid ([256]=0)
        if ((int)incl >= r && (int)excl < r) {
            s_prefix = pref | ((unsigned)tid << shift);
            s_r = r - (int)excl;
        }
        __syncthreads();
    }

    const unsigned tkey = s_prefix;  // exact key of the K-th largest
    if (tid < 2) s_GE[tid] = 0u;
    __syncthreads();
    {
        unsigned g = 0, e = 0;
        for (int i = tid; i < N_HID; i += 256) {
            unsigned k = sk[i];
            g += (k > tkey);
            e += (k == tkey);
        }
        if (g) atomicAdd(&s_GE[0], g);
        if (e) atomicAdd(&s_GE[1], e);
    }
    __syncthreads();
    const int take_eq = K_WIN - (int)s_GE[0];  // equals to take, lowest index first

    float l[10];
    #pragma unroll
    for (int cc = 0; cc < 10; ++cc) l[cc] = 0.f;
    for (int i = tid; i < N_HID; i += 256) {
        const unsigned k = sk[i];
        bool win = (k > tkey);
        if (!win && k == tkey) {
            int rnk = 0;
            for (int j = 0; j < i; ++j) rnk += (sk[j] == tkey);
            win = (rnk < take_eq);
        }
        if (win) {
            const float hv = sh[i];
            #pragma unroll
            for (int cc = 0; cc < 10; ++cc)
                l[cc] = fmaf(hv, w2[cc * N_HID + i], l[cc]);
        }
    }
    #pragma unroll
    for (int off = 32; off > 0; off >>= 1) {
        #pragma unroll
        for (int cc = 0; cc < 10; ++cc)
            l[cc] += __shfl_down(l[cc], off);
    }
    const int wave = tid >> 6;
    if ((tid & 63) == 0) {
        #pragma unroll
        for (int cc = 0; cc < 10; ++cc) partial[wave][cc] = l[cc];
    }
    __syncthreads();
    if (tid == 0) {
        float lg[10];
        #pragma unroll
        for (int cc = 0; cc < 10; ++cc)
            lg[cc] = partial[0][cc] + partial[1][cc] + partial[2][cc] + partial[3][cc] + b2[cc];
        float mx = lg[0];
        #pragma unroll
        for (int cc = 1; cc < 10; ++cc) mx = fmaxf(mx, lg[cc]);
        float s = 0.f;
        #pragma unroll
        for (int cc = 0; cc < 10; ++cc) s += expf(lg[cc] - mx);
        const float lse = mx + logf(s);
        #pragma unroll
        for (int cc = 0; cc < 10; ++cc)
            out[(size_t)row * 10 + cc] = lg[cc] - lse;
    }
}

// ---------------------------------------------------------------------------
extern "C" void kernel_launch(void* const* d_in, const int* in_sizes, int n_in,
                              void* d_out, int out_size, void* d_ws, size_t ws_size,
                              hipStream_t stream) {
    const float* x    = (const float*)d_in[0];
    const float* w1   = (const float*)d_in[1];
    const float* b1   = (const float*)d_in[2];
    const float* w2   = (const float*)d_in[3];
    const float* b2   = (const float*)d_in[4];
    const float* duty = (const float*)d_in[5];
    float* out = (float*)d_out;

    float* h     = (float*)d_ws;                                   // 131 MB
    float* boost = (float*)((char*)d_ws +
                            (size_t)B_ROWS * N_HID * sizeof(float));  // 8 KB

    boost_kernel<<<8, 256, 0, stream>>>(duty, boost);
    gemm_fp32_kernel<<<dim3(16, 128), 256, 0, stream>>>(x, w1, b1, h);
    topk_logits_kernel<<<B_ROWS, 256, 0, stream>>>(h, boost, w2, b2, out);
}

// Round 3
// 745.821 us; speedup vs baseline: 4.2384x; 1.5271x over previous
//
#include <hip/hip_runtime.h>
#include <cmath>

#define B_ROWS 16384
#define IN_DIM 784
#define N_HID  2000
#define K_WIN  200

// ---------------------------------------------------------------------------
// Phase 0a: boost[i] = expf(0.1f - duty[i])
// ---------------------------------------------------------------------------
__global__ __launch_bounds__(256) void boost_kernel(const float* __restrict__ duty,
                                                    float* __restrict__ boost) {
    int i = blockIdx.x * 256 + threadIdx.x;
    if (i < N_HID) boost[i] = expf(0.1f - duty[i]);
}

// ---------------------------------------------------------------------------
// Phase 0b: w2t[i*12 + c] = w2[c*2000 + i]  (48B-aligned row per hidden unit)
// ---------------------------------------------------------------------------
__global__ __launch_bounds__(256) void w2t_kernel(const float* __restrict__ w2,
                                                  float* __restrict__ w2t) {
    int t = blockIdx.x * 256 + threadIdx.x;
    if (t < N_HID * 10) {
        int i = t / 10, c = t - i * 10;
        w2t[i * 12 + c] = w2[c * N_HID + i];
    }
}

// ---------------------------------------------------------------------------
// Phase 1: h = x @ W1^T + b1, fp32.  128x128 tile, BK=16, 256 threads,
// 8x8 microtile as split 4+4 (cols tx*4 and 64+tx*4; rows ty*4 and 64+ty*4)
// -> all LDS b128 reads are 2-way-or-broadcast (conflict-free per m136).
// Per-output k-summation order identical to round 2 (bit-identical h).
// ---------------------------------------------------------------------------
__global__ __launch_bounds__(256) void gemm_fp32_kernel(const float* __restrict__ x,
                                                        const float* __restrict__ w1,
                                                        const float* __restrict__ b1,
                                                        float* __restrict__ h) {
    __shared__ float As[16][132] __attribute__((aligned(16)));   // [k][m]
    __shared__ float Bs[16][132] __attribute__((aligned(16)));   // [k][n]
    const int tid = threadIdx.x;
    const int n0 = blockIdx.x * 128;
    const int m0 = blockIdx.y * 128;
    const int tx = tid & 15;        // n microtile
    const int ty = tid >> 4;        // m microtile
    const int r  = tid >> 2;        // 0..63 staging row
    const int c  = (tid & 3) << 2;  // 0,4,8,12 staging k-offset

    const int nb0 = n0 + r;
    const int nb1 = (n0 + r + 64 < N_HID) ? (n0 + r + 64) : (N_HID - 1);

    float acc[8][8] = {};

    for (int k0 = 0; k0 < IN_DIM; k0 += 16) {
        float4 a0 = *(const float4*)(x  + (size_t)(m0 + r)      * IN_DIM + k0 + c);
        float4 a1 = *(const float4*)(x  + (size_t)(m0 + r + 64) * IN_DIM + k0 + c);
        float4 b0 = *(const float4*)(w1 + (size_t)nb0           * IN_DIM + k0 + c);
        float4 b1v= *(const float4*)(w1 + (size_t)nb1           * IN_DIM + k0 + c);
        __syncthreads();
        As[c + 0][r] = a0.x;  As[c + 1][r] = a0.y;  As[c + 2][r] = a0.z;  As[c + 3][r] = a0.w;
        As[c + 0][r + 64] = a1.x;  As[c + 1][r + 64] = a1.y;  As[c + 2][r + 64] = a1.z;  As[c + 3][r + 64] = a1.w;
        Bs[c + 0][r] = b0.x;  Bs[c + 1][r] = b0.y;  Bs[c + 2][r] = b0.z;  Bs[c + 3][r] = b0.w;
        Bs[c + 0][r + 64] = b1v.x; Bs[c + 1][r + 64] = b1v.y; Bs[c + 2][r + 64] = b1v.z; Bs[c + 3][r + 64] = b1v.w;
        __syncthreads();
        #pragma unroll
        for (int kk = 0; kk < 16; ++kk) {
            float a[8], b[8];
            *(float4*)&a[0] = *(const float4*)&As[kk][ty * 4];
            *(float4*)&a[4] = *(const float4*)&As[kk][64 + ty * 4];
            *(float4*)&b[0] = *(const float4*)&Bs[kk][tx * 4];
            *(float4*)&b[4] = *(const float4*)&Bs[kk][64 + tx * 4];
            #pragma unroll
            for (int i = 0; i < 8; ++i)
                #pragma unroll
                for (int j = 0; j < 8; ++j)
                    acc[i][j] = fmaf(a[i], b[j], acc[i][j]);
        }
    }

    const int nlo = n0 + tx * 4;        // nlo+3 <= 1983 < 2000 always: unguarded
    const int nhi = n0 + 64 + tx * 4;   // may exceed: guarded
    #pragma unroll
    for (int i = 0; i < 8; ++i) {
        const int m = m0 + ((i < 4) ? (ty * 4 + i) : (64 + ty * 4 + (i - 4)));
        float* hrow = h + (size_t)m * N_HID;
        float4 v;
        v.x = acc[i][0] + b1[nlo + 0];
        v.y = acc[i][1] + b1[nlo + 1];
        v.z = acc[i][2] + b1[nlo + 2];
        v.w = acc[i][3] + b1[nlo + 3];
        *(float4*)(hrow + nlo) = v;
        if (nhi + 3 < N_HID) {
            float4 w;
            w.x = acc[i][4] + b1[nhi + 0];
            w.y = acc[i][5] + b1[nhi + 1];
            w.z = acc[i][6] + b1[nhi + 2];
            w.w = acc[i][7] + b1[nhi + 3];
            *(float4*)(hrow + nhi) = w;
        } else {
            #pragma unroll
            for (int j = 0; j < 4; ++j)
                if (nhi + j < N_HID) hrow[nhi + j] = acc[i][4 + j] + b1[nhi + j];
        }
    }
}

// ---------------------------------------------------------------------------
// Phase 2: ONE ROW PER WAVE, zero __syncthreads.  4 rows/block.
// Keys/h in registers (8 x float4 per lane, element i = (s*64+lane)*4+j).
// 4-pass byte radix select with per-wave LDS hist; suffix-scan via shuffles;
// after the last pass the remaining rank r == number of tied keys to take
// (lowest index first, exact jax top_k semantics via ballot rank).
// ---------------------------------------------------------------------------
__global__ __launch_bounds__(256) void topk_logits_kernel(const float* __restrict__ h,
                                                          const float* __restrict__ boost,
                                                          const float* __restrict__ w2t,
                                                          const float* __restrict__ b2,
                                                          float* __restrict__ out) {
    __shared__ unsigned shist[4 * 256] __attribute__((aligned(16)));
    const int wv   = threadIdx.x >> 6;
    const int lane = threadIdx.x & 63;
    const int row  = blockIdx.x * 4 + wv;
    unsigned* hist = &shist[wv * 256];

    const float* hrow = h + (size_t)row * N_HID;
    float4 hreg[8];
    unsigned key[8][4];

    #pragma unroll
    for (int s = 0; s < 8; ++s) {
        const int idx4 = s * 64 + lane;
        if (idx4 < N_HID / 4) {
            float4 hv = *(const float4*)(hrow + idx4 * 4);
            float4 bv = *(const float4*)(boost + idx4 * 4);
            hreg[s] = hv;
            float p0 = hv.x * bv.x, p1 = hv.y * bv.y, p2 = hv.z * bv.z, p3 = hv.w * bv.w;
            unsigned u0 = __float_as_uint(p0), u1 = __float_as_uint(p1);
            unsigned u2 = __float_as_uint(p2), u3 = __float_as_uint(p3);
            key[s][0] = (u0 >> 31) ? ~u0 : (u0 | 0x80000000u);
            key[s][1] = (u1 >> 31) ? ~u1 : (u1 | 0x80000000u);
            key[s][2] = (u2 >> 31) ? ~u2 : (u2 | 0x80000000u);
            key[s][3] = (u3 >> 31) ? ~u3 : (u3 | 0x80000000u);
        } else {
            hreg[s] = make_float4(0.f, 0.f, 0.f, 0.f);
            key[s][0] = key[s][1] = key[s][2] = key[s][3] = 0u;  // < any real key
        }
    }

    unsigned pref = 0u;
    int r = K_WIN;

    #pragma unroll
    for (int pass = 3; pass >= 0; --pass) {
        const int shift = pass * 8;
        const unsigned himask = (pass == 3) ? 0u : (0xFFFFFFFFu << (shift + 8));
        hist[lane] = 0u; hist[lane + 64] = 0u; hist[lane + 128] = 0u; hist[lane + 192] = 0u;
        __builtin_amdgcn_wave_barrier();
        #pragma unroll
        for (int s = 0; s < 8; ++s)
            #pragma unroll
            for (int j = 0; j < 4; ++j) {
                unsigned k = key[s][j];
                if (((k ^ pref) & himask) == 0u)
                    atomicAdd(&hist[(k >> shift) & 255u], 1u);
            }
        __builtin_amdgcn_wave_barrier();
        uint4 hv = *(const uint4*)&hist[lane * 4];   // bins 4*lane .. 4*lane+3
        unsigned tot = hv.x + hv.y + hv.z + hv.w;
        unsigned run = tot;                           // suffix over lane totals
        #pragma unroll
        for (int off = 1; off < 64; off <<= 1) {
            unsigned t = (unsigned)__shfl_down((int)run, off);
            if (lane + off < 64) run += t;
        }
        const int above = (int)(run - tot);           // sum over lanes > me
        const int i3 = above + (int)hv.w;
        const int i2 = i3 + (int)hv.z;
        const int i1 = i2 + (int)hv.y;
        const int i0 = i1 + (int)hv.x;
        int fq = -1, fex = 0;
        if (i0 >= r && i1 < r)    { fq = 0; fex = i1; }
        if (i1 >= r && i2 < r)    { fq = 1; fex = i2; }
        if (i2 >= r && i3 < r)    { fq = 2; fex = i3; }
        if (i3 >= r && above < r) { fq = 3; fex = above; }
        unsigned long long fm = __ballot(fq >= 0);    // exactly one bit set
        int src = __builtin_ctzll(fm);
        unsigned pack = (fq >= 0)
            ? (((unsigned)(lane * 4 + fq) << 16) | (unsigned)(r - fex)) : 0u;
        pack = (unsigned)__shfl((int)pack, src);
        pref |= (pack >> 16) << shift;
        r = (int)(pack & 0xFFFFu);
    }

    const unsigned tkey = pref;
    const int take_eq = r;   // rank among equal keys == # equals to take

    // Winner mask with exact lowest-index-first tie break (lex (lane,j) order)
    unsigned winm = 0u;
    int run_eq = 0;
    #pragma unroll
    for (int s = 0; s < 8; ++s) {
        bool gt[4], eq[4];
        #pragma unroll
        for (int j = 0; j < 4; ++j) {
            unsigned k = key[s][j];
            gt[j] = (k > tkey);
            eq[j] = (k == tkey);
        }
        unsigned long long em0 = __ballot(eq[0]);
        unsigned long long em1 = __ballot(eq[1]);
        unsigned long long em2 = __ballot(eq[2]);
        unsigned long long em3 = __ballot(eq[3]);
        const unsigned long long lt = (1ull << lane) - 1ull;
        const int base_lt = __popcll(em0 & lt) + __popcll(em1 & lt) +
                            __popcll(em2 & lt) + __popcll(em3 & lt);
        int own = 0;
        #pragma unroll
        for (int j = 0; j < 4; ++j) {
            if (gt[j]) winm |= 1u << (s * 4 + j);
            else if (eq[j]) {
                if (run_eq + base_lt + own < take_eq) winm |= 1u << (s * 4 + j);
                ++own;
            }
        }
        run_eq += __popcll(em0) + __popcll(em1) + __popcll(em2) + __popcll(em3);
    }

    // Logits over winners (w2t: 12 floats per hidden unit, 48B rows)
    float l[10];
    #pragma unroll
    for (int cc = 0; cc < 10; ++cc) l[cc] = 0.f;
    #pragma unroll
    for (int s = 0; s < 8; ++s) {
        const int idx4 = s * 64 + lane;
        const float* hp = (const float*)&hreg[s];
        #pragma unroll
        for (int j = 0; j < 4; ++j) {
            if (winm & (1u << (s * 4 + j))) {
                const float hv = hp[j];
                const float* wr = w2t + (size_t)(idx4 * 4 + j) * 12;
                float4 wa = *(const float4*)wr;
                float4 wb = *(const float4*)(wr + 4);
                float2 wc = *(const float2*)(wr + 8);
                l[0] = fmaf(hv, wa.x, l[0]);
                l[1] = fmaf(hv, wa.y, l[1]);
                l[2] = fmaf(hv, wa.z, l[2]);
                l[3] = fmaf(hv, wa.w, l[3]);
                l[4] = fmaf(hv, wb.x, l[4]);
                l[5] = fmaf(hv, wb.y, l[5]);
                l[6] = fmaf(hv, wb.z, l[6]);
                l[7] = fmaf(hv, wb.w, l[7]);
                l[8] = fmaf(hv, wc.x, l[8]);
                l[9] = fmaf(hv, wc.y, l[9]);
            }
        }
    }
    #pragma unroll
    for (int off = 32; off > 0; off >>= 1)
        #pragma unroll
        for (int cc = 0; cc < 10; ++cc)
            l[cc] += __shfl_down(l[cc], off);

    if (lane == 0) {
        float lg[10];
        #pragma unroll
        for (int cc = 0; cc < 10; ++cc) lg[cc] = l[cc] + b2[cc];
        float mx = lg[0];
        #pragma unroll
        for (int cc = 1; cc < 10; ++cc) mx = fmaxf(mx, lg[cc]);
        float s = 0.f;
        #pragma unroll
        for (int cc = 0; cc < 10; ++cc) s += expf(lg[cc] - mx);
        const float lse = mx + logf(s);
        float* orow = out + (size_t)row * 10;
        #pragma unroll
        for (int cc = 0; cc < 10; ++cc) orow[cc] = lg[cc] - lse;
    }
}

// ---------------------------------------------------------------------------
extern "C" void kernel_launch(void* const* d_in, const int* in_sizes, int n_in,
                              void* d_out, int out_size, void* d_ws, size_t ws_size,
                              hipStream_t stream) {
    const float* x    = (const float*)d_in[0];
    const float* w1   = (const float*)d_in[1];
    const float* b1   = (const float*)d_in[2];
    const float* w2   = (const float*)d_in[3];
    const float* b2   = (const float*)d_in[4];
    const float* duty = (const float*)d_in[5];
    float* out = (float*)d_out;

    const size_t hbytes = (size_t)B_ROWS * N_HID * sizeof(float);  // 131.072 MB
    float* h     = (float*)d_ws;
    float* boost = (float*)((char*)d_ws + hbytes);                 // 8 KB, 16B-aligned
    float* w2t   = (float*)((char*)d_ws + hbytes + 8192);          // 96 KB

    boost_kernel<<<8, 256, 0, stream>>>(duty, boost);
    w2t_kernel<<<(N_HID * 10 + 255) / 256, 256, 0, stream>>>(w2, w2t);
    gemm_fp32_kernel<<<dim3(16, 128), 256, 0, stream>>>(x, w1, b1, h);
    topk_logits_kernel<<<B_ROWS / 4, 256, 0, stream>>>(h, boost, w2t, b2, out);
}